// Round 2
// baseline (259.909 us; speedup 1.0000x reference)
//
#include <hip/hip_runtime.h>
#include <stdint.h>

// Problem constants
#define CC    1024
#define EE    320
#define KN    640         // G*E
#define DD    256
#define MTOT  16384       // B*T
#define NBLK  640         // GEMM grid
#define OUT4  2097152     // output float4 count
#define ZPB   3277        // zero-fill float4s per block (640*3277 >= OUT4)
#define MARGIN 2.0f       // candidate gate: 15 sigma of bf16 dropped-term error

typedef __attribute__((ext_vector_type(8))) short short8;
typedef __attribute__((ext_vector_type(4))) float f32x4;
typedef __attribute__((ext_vector_type(4))) int   i32x4;

__device__ __forceinline__ unsigned int f32_orderable(float x) {
    unsigned int b = __float_as_uint(x);
    return (b & 0x80000000u) ? ~b : (b | 0x80000000u);
}

__device__ __forceinline__ unsigned short bf16_rne(float x) {
    unsigned int u = __float_as_uint(x);
    return (unsigned short)((u + 0x7FFFu + ((u >> 16) & 1u)) >> 16);
}

__global__ void init_slots_kernel(unsigned long long* __restrict__ slots) {
    if (threadIdx.x < 17) slots[threadIdx.x] = 0ull;
}

// ------------------- prep: W -> bf16 frag-major (B2F) + slot/counter init -------------------
// Frag-major layout: unit = (row/16)*32 + (k/32);
//   B2F[unit*512 + lane*8 + j] = bf16 of W[unit_row*16 + (lane&15)][kc*32 + (lane>>4)*8 + j]
__global__ __launch_bounds__(256)
void prep_kernel(const float* __restrict__ W, unsigned short* __restrict__ B2F,
                 unsigned long long* __restrict__ slots) {
    if (blockIdx.x == 0 && threadIdx.x < 17) slots[threadIdx.x] = 0ull;
    const int lane = threadIdx.x & 63;
    int unit = blockIdx.x * 4 + (threadIdx.x >> 6);     // 1280 units total
    int rt = unit >> 5, kc = unit & 31;
    int row = rt * 16 + (lane & 15);
    int col = kc * 32 + ((lane >> 4) << 3);
    const float* p = W + (size_t)row * CC + col;
    float4 v0 = *(const float4*)p;
    float4 v1 = *(const float4*)(p + 4);
    short8 hi;
    hi[0] = (short)bf16_rne(v0.x); hi[1] = (short)bf16_rne(v0.y);
    hi[2] = (short)bf16_rne(v0.z); hi[3] = (short)bf16_rne(v0.w);
    hi[4] = (short)bf16_rne(v1.x); hi[5] = (short)bf16_rne(v1.y);
    hi[6] = (short)bf16_rne(v1.z); hi[7] = (short)bf16_rne(v1.w);
    *(short8*)(B2F + (size_t)unit * 512 + lane * 8) = hi;
}

// ------------------- fused: wave-autonomous bf16 MFMA GEMM + argmax + refine + scatter ----
// No LDS, no barriers in the K-loop. Each wave loads its A fragments DIRECTLY from fp32 X
// (the 16x16x32 A layout is row-major-loadable: lane l <- row l&15, k (l>>4)*8..+7, i.e.
// two float4 per frag), converts in-register via v_cvt_pk_bf16_f32, and loads B fragments
// from L2-resident B2F. Software-pipelined in registers: A 3 deep (HBM latency), B 2 deep
// (L2 latency). Full 32-step unroll -> all stage indices & A offsets compile-time.
__global__ __launch_bounds__(256, 2)
void vq_fused(const float* __restrict__ X,
              const unsigned short* __restrict__ B2F,
              const float* __restrict__ W,
              const float* __restrict__ bias,
              const float* __restrict__ codebook,
              float* __restrict__ out,
              unsigned long long* __restrict__ slots,
              unsigned int* __restrict__ counter) {
    __shared__ float redf[4];
    __shared__ int cnt_s;
    __shared__ int cand_s[128];
    __shared__ unsigned int done_s;
    __shared__ unsigned long long s16[16];

    const int tid  = threadIdx.x;
    const int lane = tid & 63;
    const int wave = tid >> 6;

    // XCD swizzle: one XCD covers 16 m-tiles x all 5 n-tiles (n fastest) -> X/B2F L2 reuse.
    const int l   = blockIdx.x;        // 0..639
    const int xcd = l & 7;
    const int w   = l >> 3;
    const int mt  = xcd * 16 + w / 5;
    const int nt  = w % 5;
    const int m0  = mt * 128;
    const int n0  = nt * 128;
    const int wm  = (wave >> 1) * 64;
    const int wn  = (wave & 1) * 64;

    // A: per-lane row base; all K-step addresses are base + immediate (t*128B <= 3984).
    const float* Ap[4];
#pragma unroll
    for (int f = 0; f < 4; f++)
        Ap[f] = X + (size_t)(m0 + wm + f * 16 + (lane & 15)) * CC + ((lane >> 4) << 3);
    // B: frag-major bf16, kc stride = 512 shorts
    const unsigned short* Bq[4];
#pragma unroll
    for (int f = 0; f < 4; f++)
        Bq[f] = B2F + ((size_t)(((n0 + wn) >> 4) + f) * 32) * 512 + lane * 8;

    f32x4 acc[4][4] = {};
    float4 As[3][4][2];     // 3-deep A pipeline (fp32, converted at use)
    short8 Bs[2][4];        // 2-deep B pipeline (bf16, used directly)

#define LOADA(S, T)                                                          \
    {                                                                        \
        _Pragma("unroll")                                                    \
        for (int f = 0; f < 4; f++) {                                        \
            As[S][f][0] = *(const float4*)(Ap[f] + (T) * 32);                \
            As[S][f][1] = *(const float4*)(Ap[f] + (T) * 32 + 4);            \
        }                                                                    \
    }
#define LOADB(S, T)                                                          \
    {                                                                        \
        _Pragma("unroll")                                                    \
        for (int f = 0; f < 4; f++)                                          \
            Bs[S][f] = *(const short8*)(Bq[f] + (size_t)(T) * 512);          \
    }

    // ---- prologue: fill the pipeline, then zero-fill output under the load latency ----
    LOADA(0, 0)
    LOADB(0, 0)
    LOADA(1, 1)
    LOADB(1, 1)
    LOADA(2, 2)
    {
        int base = l * ZPB;
        f32x4 z = {0.f, 0.f, 0.f, 0.f};
        for (int j = 0; j < 13; j++) {
            int o = j * 256 + tid;
            int idx = base + o;
            if (o < ZPB && idx < OUT4)
                __builtin_nontemporal_store(z, (f32x4*)out + idx);
        }
    }

#define CVTPK(d, lo, hi) asm("v_cvt_pk_bf16_f32 %0, %1, %2" : "=v"(d) : "v"(lo), "v"(hi))

    // ---- K-loop: 32 steps of K=32, barrier-free, register-pipelined ----
#pragma unroll
    for (int t = 0; t < 32; t++) {
        const int ia = t % 3;
        const int ib = t % 2;
        short8 af[4];
#pragma unroll
        for (int f = 0; f < 4; f++) {
            unsigned c0, c1, c2, c3;
            CVTPK(c0, As[ia][f][0].x, As[ia][f][0].y);
            CVTPK(c1, As[ia][f][0].z, As[ia][f][0].w);
            CVTPK(c2, As[ia][f][1].x, As[ia][f][1].y);
            CVTPK(c3, As[ia][f][1].z, As[ia][f][1].w);
            i32x4 pk = {(int)c0, (int)c1, (int)c2, (int)c3};
            af[f] = *(short8*)&pk;
        }
        // refill A stage just consumed (for step t+3)
        if (t + 3 < 32) LOADA(ia, t + 3)
#pragma unroll
        for (int ti = 0; ti < 4; ti++)
#pragma unroll
            for (int tj = 0; tj < 4; tj++)
                acc[ti][tj] = __builtin_amdgcn_mfma_f32_16x16x32_bf16(
                    af[ti], Bs[ib][tj], acc[ti][tj], 0, 0, 0);
        // refill B stage just consumed (for step t+2)
        if (t + 2 < 32) LOADB(ib, t + 2)
    }
#undef CVTPK
#undef LOADA
#undef LOADB

    // ---- epilogue: block max of approx logits ----
    // C/D layout (16x16x32): col = lane&15, row = (lane>>4)*4 + reg
    float bias4[4];
#pragma unroll
    for (int tj = 0; tj < 4; tj++) bias4[tj] = bias[n0 + wn + tj * 16 + (lane & 15)];

    float vmax = -3.0e38f;
#pragma unroll
    for (int ti = 0; ti < 4; ti++)
#pragma unroll
        for (int tj = 0; tj < 4; tj++)
#pragma unroll
            for (int rr = 0; rr < 4; rr++)
                vmax = fmaxf(vmax, acc[ti][tj][rr] + bias4[tj]);
#pragma unroll
    for (int off = 32; off > 0; off >>= 1)
        vmax = fmaxf(vmax, __shfl_down(vmax, off, 64));
    if (lane == 0) redf[wave] = vmax;
    if (tid == 0) cnt_s = 0;
    __syncthreads();
    float bm = fmaxf(fmaxf(redf[0], redf[1]), fmaxf(redf[2], redf[3]));
    float thresh = bm - MARGIN;

    // ---- collect candidates within MARGIN of block max ----
#pragma unroll
    for (int ti = 0; ti < 4; ti++) {
#pragma unroll
        for (int rr = 0; rr < 4; rr++) {
            int m = m0 + wm + ti * 16 + (lane >> 4) * 4 + rr;
#pragma unroll
            for (int tj = 0; tj < 4; tj++) {
                float v = acc[ti][tj][rr] + bias4[tj];
                if (v >= thresh) {
                    int n = n0 + wn + tj * 16 + (lane & 15);
                    int idx = atomicAdd(&cnt_s, 1);
                    if (idx < 128) cand_s[idx] = (m << 10) | n;
                }
            }
        }
    }
    __syncthreads();
    int cnt = cnt_s < 128 ? cnt_s : 128;

    // ---- exact fp32 refine of each candidate (cooperative 1024-dot) ----
    for (int i = 0; i < cnt; i++) {
        int mc = cand_s[i] >> 10;
        int nc = cand_s[i] & 1023;
        float4 xv = *(const float4*)(X + (size_t)mc * CC + tid * 4);
        float4 wv = *(const float4*)(W + (size_t)nc * CC + tid * 4);
        float p = xv.x * wv.x + xv.y * wv.y + xv.z * wv.z + xv.w * wv.w;
#pragma unroll
        for (int off = 32; off > 0; off >>= 1) p += __shfl_down(p, off, 64);
        if (lane == 0) redf[wave] = p;
        __syncthreads();
        if (tid == 0) {
            float tot = redf[0] + redf[1] + redf[2] + redf[3] + bias[nc];
            unsigned int c = (unsigned int)((mc & 1023) * KN + nc);
            unsigned long long pk =
                ((unsigned long long)f32_orderable(tot) << 32) |
                (unsigned long long)(~c);
            atomicMax(slots + (mc >> 10), pk);
        }
        __syncthreads();
    }

    if (tid == 0) {
        __threadfence();
        done_s = atomicAdd(counter, 1u);
    }
    __syncthreads();

    // ---- last block scatters the 16 codebook rows ----
    if (done_s == NBLK - 1) {
        if (tid < 16) s16[tid] = atomicAdd(slots + tid, 0ull);   // coherent cross-XCD read
        __syncthreads();
        int rr  = tid >> 4;
        int seg = tid & 15;
        unsigned long long p = s16[rr];
        unsigned int c = ~(unsigned int)(p & 0xFFFFFFFFull);
        int tl = (int)(c / KN);
        int kg = (int)(c % KN);
        int b  = rr >> 1, h = rr & 1;
        int nstar = b * 2048 + h * 1024 + tl;
        int g = kg / EE;
        const float4* src = (const float4*)(codebook + (size_t)kg * DD) + seg * 4;
        float4* dst = (float4*)(out + (size_t)nstar * 512 + (size_t)g * DD) + seg * 4;
#pragma unroll
        for (int j = 0; j < 4; j++) dst[j] = src[j];
    }
}

// ------------------- fallback-only kernels (ws too small; not used in practice) ------------
__global__ __launch_bounds__(256)
void zs_kernel(const unsigned long long* __restrict__ slots,
               const float* __restrict__ codebook,
               float4* __restrict__ out4) {
    int i4 = blockIdx.x * 256 + threadIdx.x;
    int n  = i4 >> 7;
    int c4 = i4 & 127;
    int b  = n >> 11;
    int h  = (n >> 10) & 1;
    unsigned long long p = slots[b * 2 + h];
    unsigned int c = ~(unsigned int)(p & 0xFFFFFFFFull);
    int tl = (int)(c / KN);
    int kg = (int)(c % KN);
    int nstar = b * 2048 + h * 1024 + tl;
    int g = kg / EE;
    float4 v = make_float4(0.f, 0.f, 0.f, 0.f);
    if (n == nstar && (c4 >> 6) == g)
        v = ((const float4*)codebook)[kg * 64 + (c4 & 63)];
    out4[i4] = v;
}

#define BM 128
#define BN 64
#define BK 32
#define LDA (BM + 4)
#define LDB (BN + 4)

__global__ __launch_bounds__(128)
void gemm_argmax_f32(const float* __restrict__ X, const float* __restrict__ W,
                     const float* __restrict__ bias,
                     unsigned long long* __restrict__ slots) {
    __shared__ float Asf[BK][LDA];
    __shared__ float Bsf[BK][LDB];
    const int tid = threadIdx.x;
    const int m0 = blockIdx.y * BM;
    const int n0 = blockIdx.x * BN;
    const int tx = tid & 7, ty = tid >> 3;
    float acc[8][8];
#pragma unroll
    for (int i = 0; i < 8; i++)
#pragma unroll
        for (int j = 0; j < 8; j++) acc[i][j] = 0.0f;
    const int lm = tid >> 3, lk = (tid & 7) * 4;
    const float* Xb = X + (size_t)m0 * CC;
    const float* Wb = W + (size_t)n0 * CC;
    for (int k0 = 0; k0 < CC; k0 += BK) {
#pragma unroll
        for (int rr = 0; rr < 8; rr++) {
            int m = rr * 16 + lm;
            float4 v = *(const float4*)(Xb + (size_t)m * CC + k0 + lk);
            Asf[lk + 0][m] = v.x; Asf[lk + 1][m] = v.y; Asf[lk + 2][m] = v.z; Asf[lk + 3][m] = v.w;
        }
#pragma unroll
        for (int rr = 0; rr < 4; rr++) {
            int m = rr * 16 + lm;
            float4 v = *(const float4*)(Wb + (size_t)m * CC + k0 + lk);
            Bsf[lk + 0][m] = v.x; Bsf[lk + 1][m] = v.y; Bsf[lk + 2][m] = v.z; Bsf[lk + 3][m] = v.w;
        }
        __syncthreads();
#pragma unroll
        for (int kk = 0; kk < BK; kk++) {
            float4 A0 = *(const float4*)&Asf[kk][ty * 8];
            float4 A1 = *(const float4*)&Asf[kk][ty * 8 + 4];
            float4 B0 = *(const float4*)&Bsf[kk][tx * 8];
            float4 B1 = *(const float4*)&Bsf[kk][tx * 8 + 4];
            float a[8] = {A0.x, A0.y, A0.z, A0.w, A1.x, A1.y, A1.z, A1.w};
            float b[8] = {B0.x, B0.y, B0.z, B0.w, B1.x, B1.y, B1.z, B1.w};
#pragma unroll
            for (int i = 0; i < 8; i++)
#pragma unroll
                for (int j = 0; j < 8; j++) acc[i][j] = fmaf(a[i], b[j], acc[i][j]);
        }
        __syncthreads();
    }
    unsigned long long best = 0ull;
#pragma unroll
    for (int i = 0; i < 8; i++) {
        int mg = m0 + ty * 8 + i;
        int tl = mg & 1023;
#pragma unroll
        for (int j = 0; j < 8; j++) {
            int kg = n0 + tx * 8 + j;
            float v = acc[i][j] + bias[kg];
            unsigned int c = (unsigned int)(tl * KN + kg);
            unsigned long long p = ((unsigned long long)f32_orderable(v) << 32) |
                                   (unsigned long long)(~c);
            if (p > best) best = p;
        }
    }
#pragma unroll
    for (int off = 32; off > 0; off >>= 1) {
        unsigned long long o = __shfl_down(best, off, 64);
        if (o > best) best = o;
    }
    __shared__ unsigned long long red2[2];
    if ((tid & 63) == 0) red2[tid >> 6] = best;
    __syncthreads();
    if (tid == 0) {
        unsigned long long b0 = red2[0], b1 = red2[1];
        atomicMax(slots + (m0 >> 10), b0 > b1 ? b0 : b1);
    }
}

extern "C" void kernel_launch(void* const* d_in, const int* in_sizes, int n_in,
                              void* d_out, int out_size, void* d_ws, size_t ws_size,
                              hipStream_t stream) {
    const float* X        = (const float*)d_in[0];  // (8,2048,1024)
    const float* W        = (const float*)d_in[1];  // (640,1024)
    const float* bias     = (const float*)d_in[2];  // (640,)
    const float* codebook = (const float*)d_in[3];  // (640,256)
    float* out = (float*)d_out;                     // (8,2048,512) fp32

    unsigned long long* slots = (unsigned long long*)d_ws;   // [0..15] slots, [16] counter
    unsigned int* counter = (unsigned int*)(slots + 16);
    const size_t B_off   = 256;
    const size_t B_bytes = (size_t)KN * CC * 2;     // 1,310,720 (bf16 frag-major W)
    const size_t need = B_off + B_bytes;

    if (ws_size >= need) {
        unsigned short* B2F = (unsigned short*)((char*)d_ws + B_off);
        hipLaunchKernelGGL(prep_kernel, dim3(320), dim3(256), 0, stream, W, B2F, slots);
        hipLaunchKernelGGL(vq_fused, dim3(NBLK), dim3(256), 0, stream,
                           X, B2F, W, bias, codebook, out, slots, counter);
    } else {
        hipLaunchKernelGGL(init_slots_kernel, dim3(1), dim3(64), 0, stream, slots);
        hipLaunchKernelGGL(gemm_argmax_f32, dim3(KN / BN, MTOT / BM), dim3(128), 0, stream,
                           X, W, bias, slots);
        hipLaunchKernelGGL(zs_kernel, dim3(OUT4 / 256), dim3(256), 0, stream,
                           slots, codebook, (float4*)out);
    }
}

// Round 3
// 191.599 us; speedup vs baseline: 1.3565x; 1.3565x over previous
//
#include <hip/hip_runtime.h>
#include <stdint.h>

// Problem constants
#define CC    1024
#define EE    320
#define KN    640         // G*E
#define DD    256
#define MTOT  16384       // B*T
#define NBLK  640         // GEMM grid
#define OUT4  2097152     // output float4 count
#define MARGIN 2.0f       // candidate gate: 15 sigma of hi*hi dropped-term error

typedef __attribute__((ext_vector_type(8))) short short8;
typedef __attribute__((ext_vector_type(4))) float f32x4;

__device__ __forceinline__ unsigned int f32_orderable(float x) {
    unsigned int b = __float_as_uint(x);
    return (b & 0x80000000u) ? ~b : (b | 0x80000000u);
}

__device__ __forceinline__ unsigned short bf16_rne(float x) {
    unsigned int u = __float_as_uint(x);
    return (unsigned short)((u + 0x7FFFu + ((u >> 16) & 1u)) >> 16);
}

__global__ void init_slots_kernel(unsigned long long* __restrict__ slots) {
    if (threadIdx.x < 17) slots[threadIdx.x] = 0ull;
}

// ------------------- fused convert (hi-only) + zero-fill + slot init -------------------
// Fragment-major hi-only layout (A2F from X, B2F from W):
//   unit = rowTile*32 + kc   (rowTile = row/16, kc = k/32)
//   buf[unit*512 + lane*8 + j] = bf16_hi of M[rowTile*16 + (lane&15)][kc*32 + (lane>>4)*8 + j]
// -> GEMM frag load = base + lane*16B (coalesced 1KB/wave, exact 16x16x32 operand layout).
__global__ __launch_bounds__(256)
void convert_kernel(const float* __restrict__ X, const float* __restrict__ W,
                    unsigned short* __restrict__ A2F, unsigned short* __restrict__ B2F,
                    unsigned long long* __restrict__ slots, float* __restrict__ out) {
    const int bid = blockIdx.x;
    const int tid = threadIdx.x;
    {   // zero-fill share of output (blocks 0..8191 cover all 2,097,152 float4s)
        int zidx = bid * 256 + tid;
        f32x4 z = {0.f, 0.f, 0.f, 0.f};
        if (zidx < OUT4) __builtin_nontemporal_store(z, (f32x4*)out + zidx);
    }
    const int lane = tid & 63;
    const float* src;
    unsigned short* dst;
    int unit;
    if (bid < 8192) {                      // X: units = 1024 mb x 32 kc
        unit = bid * 4 + (tid >> 6);
        src = X; dst = A2F;
    } else {                               // W: 1280 units -> 320 blocks
        if (bid == 8192 && tid < 17) slots[tid] = 0ull;   // 16 slots + counter
        unit = (bid - 8192) * 4 + (tid >> 6);
        src = W; dst = B2F;
    }
    int rt = unit >> 5, kc = unit & 31;
    int row = rt * 16 + (lane & 15);
    int col = kc * 32 + ((lane >> 4) << 3);
    const float* p = src + (size_t)row * CC + col;
    float4 v0 = *(const float4*)p;
    float4 v1 = *(const float4*)(p + 4);
    short8 hi;
    hi[0] = (short)bf16_rne(v0.x); hi[1] = (short)bf16_rne(v0.y);
    hi[2] = (short)bf16_rne(v0.z); hi[3] = (short)bf16_rne(v0.w);
    hi[4] = (short)bf16_rne(v1.x); hi[5] = (short)bf16_rne(v1.y);
    hi[6] = (short)bf16_rne(v1.z); hi[7] = (short)bf16_rne(v1.w);
    *(short8*)(dst + (size_t)unit * 512 + lane * 8) = hi;
}

// ------------------- 2-ahead bf16 MFMA GEMM + margin argmax + exact refine + scatter ----------
// approx C = Xhi * Whi^T. No LDS, no barriers in the K-loop: A/B frags direct from L2
// (fragment-major). Register pipeline: A 3 buffers (2-ahead, covers L2/L3 latency on the
// 4MB/XCD A-stream), B 2 buffers (1-ahead, B2F is L2-hot). Rolled 6-step rotation body
// (lcm(3,2)) keeps all buffer indices compile-time at ~80 stage VGPRs -> compiler emits
// counted vmcnt(12)-style waits, loads never fully drain. Epilogue: block-max ->
// candidates within MARGIN -> cooperative EXACT fp32 dot from X,W -> packed atomicMax.
// Last block (device counter) scatters the 16 codebook rows.
__global__ __launch_bounds__(256, 3)
void gemm_argmax_mfma(const unsigned short* __restrict__ A2F,
                      const unsigned short* __restrict__ B2F,
                      const float* __restrict__ X,
                      const float* __restrict__ W,
                      const float* __restrict__ bias,
                      const float* __restrict__ codebook,
                      float* __restrict__ out,
                      unsigned long long* __restrict__ slots,
                      unsigned int* __restrict__ counter) {
    __shared__ float redf[4];
    __shared__ int cnt_s;
    __shared__ int cand_s[128];
    __shared__ unsigned int done_s;
    __shared__ unsigned long long s16[16];

    const int tid  = threadIdx.x;
    const int lane = tid & 63;
    const int wave = tid >> 6;

    // XCD swizzle: one XCD covers 16 m-tiles x all 5 n-tiles (n fastest) -> A2F L2 reuse.
    const int l   = blockIdx.x;        // 0..639
    const int xcd = l & 7;
    const int w   = l >> 3;
    const int mt  = xcd * 16 + w / 5;
    const int nt  = w % 5;
    const int m0 = mt * 128;
    const int n0 = nt * 128;

    const int wm = (wave >> 1) * 64;
    const int wn = (wave & 1) * 64;

    // 32-bit element offsets into A2F/B2F (uniform base + voffset addressing)
    unsigned aoff[4], boff[4];
#pragma unroll
    for (int t = 0; t < 4; t++) {
        aoff[t] = (unsigned)((((m0 + wm) >> 4) + t) * 32) * 512u + (unsigned)(lane * 8);
        boff[t] = (unsigned)((((n0 + wn) >> 4) + t) * 32) * 512u + (unsigned)(lane * 8);
    }

    f32x4 acc[4][4] = {};
    short8 a0[4], a1[4], a2[4], b0[4], b1[4];

#define REFA(BUF)                                                        \
    {                                                                    \
        _Pragma("unroll")                                                \
        for (int f = 0; f < 4; f++) {                                    \
            BUF[f] = *(const short8*)(A2F + aoff[f]);                    \
            aoff[f] += 512;                                              \
        }                                                                \
    }
#define REFB(BUF)                                                        \
    {                                                                    \
        _Pragma("unroll")                                                \
        for (int f = 0; f < 4; f++) {                                    \
            BUF[f] = *(const short8*)(B2F + boff[f]);                    \
            boff[f] += 512;                                              \
        }                                                                \
    }
#define MFMAS(AB, BB)                                                    \
    {                                                                    \
        _Pragma("unroll")                                                \
        for (int ti = 0; ti < 4; ti++)                                   \
            _Pragma("unroll")                                            \
            for (int tj = 0; tj < 4; tj++)                               \
                acc[ti][tj] = __builtin_amdgcn_mfma_f32_16x16x32_bf16(   \
                    AB[ti], BB[tj], acc[ti][tj], 0, 0, 0);               \
    }

    // prologue: A buffers hold data 0,1,2; B buffers hold data 0,1
    REFA(a0) REFB(b0) REFA(a1) REFB(b1) REFA(a2)

    MFMAS(a0, b0)                          // t = 0
    // invariant at step t: A buf (t%3) holds data t, B buf (t%2) holds data t.
    // Each slot refills the buffer consumed last step (A: data t+2, B: data t+1),
    // issued BEFORE the MFMAs -> loads stay >=2 (A) / >=1 (B) steps ahead.
    for (int i = 0; i < 5; i++) {          // t = 1..30 (6-step rotation body)
        REFA(a0) REFB(b0) MFMAS(a1, b1)    // t%6==1
        REFA(a1) REFB(b1) MFMAS(a2, b0)    // t%6==2
        REFA(a2) REFB(b0) MFMAS(a0, b1)    // t%6==3
        REFA(a0) REFB(b1) MFMAS(a1, b0)    // t%6==4
        REFA(a1) REFB(b0) MFMAS(a2, b1)    // t%6==5
        REFA(a2) REFB(b1) MFMAS(a0, b0)    // t%6==0
    }
    // NOTE: the final REFA (t=30, data "32") reads 1 unit past this tile's K range.
    // For the last m-tile that is <=2KB past A2F's end, which lands inside the
    // B2F region of the same workspace allocation -> in-bounds, value unused.
    MFMAS(a1, b1)                          // t = 31

#undef REFA
#undef REFB
#undef MFMAS

    // ---- epilogue: block max of approx logits ----
    // C/D layout (16x16x32): col = lane&15, row = (lane>>4)*4 + reg
    float bias4[4];
#pragma unroll
    for (int tj = 0; tj < 4; tj++) bias4[tj] = bias[n0 + wn + tj * 16 + (lane & 15)];

    float vmax = -3.0e38f;
#pragma unroll
    for (int ti = 0; ti < 4; ti++)
#pragma unroll
        for (int tj = 0; tj < 4; tj++)
#pragma unroll
            for (int r = 0; r < 4; r++)
                vmax = fmaxf(vmax, acc[ti][tj][r] + bias4[tj]);
#pragma unroll
    for (int off = 32; off > 0; off >>= 1)
        vmax = fmaxf(vmax, __shfl_down(vmax, off, 64));
    if (lane == 0) redf[wave] = vmax;
    if (tid == 0) cnt_s = 0;
    __syncthreads();
    float bm = fmaxf(fmaxf(redf[0], redf[1]), fmaxf(redf[2], redf[3]));
    float thresh = bm - MARGIN;

    // ---- collect candidates within MARGIN of block max ----
#pragma unroll
    for (int ti = 0; ti < 4; ti++) {
#pragma unroll
        for (int r = 0; r < 4; r++) {
            int m = m0 + wm + ti * 16 + (lane >> 4) * 4 + r;
#pragma unroll
            for (int tj = 0; tj < 4; tj++) {
                float v = acc[ti][tj][r] + bias4[tj];
                if (v >= thresh) {
                    int n = n0 + wn + tj * 16 + (lane & 15);
                    int idx = atomicAdd(&cnt_s, 1);
                    if (idx < 128) cand_s[idx] = (m << 10) | n;
                }
            }
        }
    }
    __syncthreads();
    int cnt = cnt_s < 128 ? cnt_s : 128;

    // ---- exact fp32 refine of each candidate (cooperative 1024-dot) ----
    for (int i = 0; i < cnt; i++) {
        int mc = cand_s[i] >> 10;
        int nc = cand_s[i] & 1023;
        float4 xv = *(const float4*)(X + (size_t)mc * CC + tid * 4);
        float4 wv = *(const float4*)(W + (size_t)nc * CC + tid * 4);
        float p = xv.x * wv.x + xv.y * wv.y + xv.z * wv.z + xv.w * wv.w;
#pragma unroll
        for (int off = 32; off > 0; off >>= 1) p += __shfl_down(p, off, 64);
        if (lane == 0) redf[wave] = p;
        __syncthreads();
        if (tid == 0) {
            float tot = redf[0] + redf[1] + redf[2] + redf[3] + bias[nc];
            unsigned int c = (unsigned int)((mc & 1023) * KN + nc);
            unsigned long long pk =
                ((unsigned long long)f32_orderable(tot) << 32) |
                (unsigned long long)(~c);
            atomicMax(slots + (mc >> 10), pk);
        }
        __syncthreads();
    }

    if (tid == 0) {
        __threadfence();
        done_s = atomicAdd(counter, 1u);
    }
    __syncthreads();

    // ---- last block scatters the 16 codebook rows ----
    if (done_s == NBLK - 1) {
        if (tid < 16) s16[tid] = atomicAdd(slots + tid, 0ull);   // coherent cross-XCD read
        __syncthreads();
        int rr  = tid >> 4;
        int seg = tid & 15;
        unsigned long long p = s16[rr];
        unsigned int c = ~(unsigned int)(p & 0xFFFFFFFFull);
        int tl = (int)(c / KN);
        int kg = (int)(c % KN);
        int b  = rr >> 1, h = rr & 1;
        int nstar = b * 2048 + h * 1024 + tl;
        int g = kg / EE;
        const float4* src = (const float4*)(codebook + (size_t)kg * DD) + seg * 4;
        float4* dst = (float4*)(out + (size_t)nstar * 512 + (size_t)g * DD) + seg * 4;
#pragma unroll
        for (int j = 0; j < 4; j++) dst[j] = src[j];
    }
}

// ------------------- fallback-only kernels (ws too small; not used in practice) ------------
__global__ __launch_bounds__(256)
void zs_kernel(const unsigned long long* __restrict__ slots,
               const float* __restrict__ codebook,
               float4* __restrict__ out4) {
    int i4 = blockIdx.x * 256 + threadIdx.x;
    int n  = i4 >> 7;
    int c4 = i4 & 127;
    int b  = n >> 11;
    int h  = (n >> 10) & 1;
    unsigned long long p = slots[b * 2 + h];
    unsigned int c = ~(unsigned int)(p & 0xFFFFFFFFull);
    int tl = (int)(c / KN);
    int kg = (int)(c % KN);
    int nstar = b * 2048 + h * 1024 + tl;
    int g = kg / EE;
    float4 v = make_float4(0.f, 0.f, 0.f, 0.f);
    if (n == nstar && (c4 >> 6) == g)
        v = ((const float4*)codebook)[kg * 64 + (c4 & 63)];
    out4[i4] = v;
}

#define BM 128
#define BN 64
#define BK 32
#define LDA (BM + 4)
#define LDB (BN + 4)

__global__ __launch_bounds__(128)
void gemm_argmax_f32(const float* __restrict__ X, const float* __restrict__ W,
                     const float* __restrict__ bias,
                     unsigned long long* __restrict__ slots) {
    __shared__ float Asf[BK][LDA];
    __shared__ float Bsf[BK][LDB];
    const int tid = threadIdx.x;
    const int m0 = blockIdx.y * BM;
    const int n0 = blockIdx.x * BN;
    const int tx = tid & 7, ty = tid >> 3;
    float acc[8][8];
#pragma unroll
    for (int i = 0; i < 8; i++)
#pragma unroll
        for (int j = 0; j < 8; j++) acc[i][j] = 0.0f;
    const int lm = tid >> 3, lk = (tid & 7) * 4;
    const float* Xb = X + (size_t)m0 * CC;
    const float* Wb = W + (size_t)n0 * CC;
    for (int k0 = 0; k0 < CC; k0 += BK) {
#pragma unroll
        for (int r = 0; r < 8; r++) {
            int m = r * 16 + lm;
            float4 v = *(const float4*)(Xb + (size_t)m * CC + k0 + lk);
            Asf[lk + 0][m] = v.x; Asf[lk + 1][m] = v.y; Asf[lk + 2][m] = v.z; Asf[lk + 3][m] = v.w;
        }
#pragma unroll
        for (int r = 0; r < 4; r++) {
            int m = r * 16 + lm;
            float4 v = *(const float4*)(Wb + (size_t)m * CC + k0 + lk);
            Bsf[lk + 0][m] = v.x; Bsf[lk + 1][m] = v.y; Bsf[lk + 2][m] = v.z; Bsf[lk + 3][m] = v.w;
        }
        __syncthreads();
#pragma unroll
        for (int kk = 0; kk < BK; kk++) {
            float4 A0 = *(const float4*)&Asf[kk][ty * 8];
            float4 A1 = *(const float4*)&Asf[kk][ty * 8 + 4];
            float4 B0 = *(const float4*)&Bsf[kk][tx * 8];
            float4 B1 = *(const float4*)&Bsf[kk][tx * 8 + 4];
            float a[8] = {A0.x, A0.y, A0.z, A0.w, A1.x, A1.y, A1.z, A1.w};
            float b[8] = {B0.x, B0.y, B0.z, B0.w, B1.x, B1.y, B1.z, B1.w};
#pragma unroll
            for (int i = 0; i < 8; i++)
#pragma unroll
                for (int j = 0; j < 8; j++) acc[i][j] = fmaf(a[i], b[j], acc[i][j]);
        }
        __syncthreads();
    }
    unsigned long long best = 0ull;
#pragma unroll
    for (int i = 0; i < 8; i++) {
        int mg = m0 + ty * 8 + i;
        int tl = mg & 1023;
#pragma unroll
        for (int j = 0; j < 8; j++) {
            int kg = n0 + tx * 8 + j;
            float v = acc[i][j] + bias[kg];
            unsigned int c = (unsigned int)(tl * KN + kg);
            unsigned long long p = ((unsigned long long)f32_orderable(v) << 32) |
                                   (unsigned long long)(~c);
            if (p > best) best = p;
        }
    }
#pragma unroll
    for (int off = 32; off > 0; off >>= 1) {
        unsigned long long o = __shfl_down(best, off, 64);
        if (o > best) best = o;
    }
    __shared__ unsigned long long red2[2];
    if ((tid & 63) == 0) red2[tid >> 6] = best;
    __syncthreads();
    if (tid == 0) {
        unsigned long long b0 = red2[0], b1 = red2[1];
        atomicMax(slots + (m0 >> 10), b0 > b1 ? b0 : b1);
    }
}

extern "C" void kernel_launch(void* const* d_in, const int* in_sizes, int n_in,
                              void* d_out, int out_size, void* d_ws, size_t ws_size,
                              hipStream_t stream) {
    const float* X        = (const float*)d_in[0];  // (8,2048,1024)
    const float* W        = (const float*)d_in[1];  // (640,1024)
    const float* bias     = (const float*)d_in[2];  // (640,)
    const float* codebook = (const float*)d_in[3];  // (640,256)
    float* out = (float*)d_out;                     // (8,2048,512) fp32

    unsigned long long* slots = (unsigned long long*)d_ws;   // [0..15] slots, [16] counter
    unsigned int* counter = (unsigned int*)(slots + 16);
    const size_t A_off   = 256;
    const size_t A_bytes = (size_t)MTOT * CC * 2;       // 33,554,432 (hi-only frag-major)
    const size_t B_off   = A_off + A_bytes;
    const size_t B_bytes = (size_t)KN * CC * 2;         // 1,310,720
    const size_t need = B_off + B_bytes;

    if (ws_size >= need) {
        unsigned short* A2F = (unsigned short*)((char*)d_ws + A_off);
        unsigned short* B2F = (unsigned short*)((char*)d_ws + B_off);
        hipLaunchKernelGGL(convert_kernel, dim3(8192 + 320), dim3(256), 0, stream,
                           X, W, A2F, B2F, slots, out);
        hipLaunchKernelGGL(gemm_argmax_mfma, dim3(NBLK), dim3(256), 0, stream,
                           A2F, B2F, X, W, bias, codebook, out, slots, counter);
    } else {
        hipLaunchKernelGGL(init_slots_kernel, dim3(1), dim3(64), 0, stream, slots);
        hipLaunchKernelGGL(gemm_argmax_f32, dim3(KN / BN, MTOT / BM), dim3(128), 0, stream,
                           X, W, bias, slots);
        hipLaunchKernelGGL(zs_kernel, dim3(OUT4 / 256), dim3(256), 0, stream,
                           slots, codebook, (float4*)out);
    }
}

// Round 4
// 170.561 us; speedup vs baseline: 1.5238x; 1.1233x over previous
//
#include <hip/hip_runtime.h>
#include <stdint.h>

// Problem constants
#define CC    1024
#define EE    320
#define KN    640         // G*E
#define DD    256
#define MTOT  16384       // B*T
#define NBLK  640         // GEMM grid
#define OUT4  2097152     // output float4 count
#define MARGIN 2.0f       // candidate gate: 15 sigma of hi*hi dropped-term error

typedef __attribute__((ext_vector_type(8))) short short8;
typedef __attribute__((ext_vector_type(4))) float f32x4;

__device__ __forceinline__ unsigned int f32_orderable(float x) {
    unsigned int b = __float_as_uint(x);
    return (b & 0x80000000u) ? ~b : (b | 0x80000000u);
}

__device__ __forceinline__ unsigned short bf16_rne(float x) {
    unsigned int u = __float_as_uint(x);
    return (unsigned short)((u + 0x7FFFu + ((u >> 16) & 1u)) >> 16);
}

__global__ void init_slots_kernel(unsigned long long* __restrict__ slots) {
    if (threadIdx.x < 17) slots[threadIdx.x] = 0ull;
}

// ------------------- fused convert (hi-only) + zero-fill + slot init -------------------
// Fragment-major hi-only layout (A2F from X, B2F from W):
//   unit = rowTile*32 + kc   (rowTile = row/16, kc = k/32)
//   buf[unit*512 + lane*8 + j] = bf16_hi of M[rowTile*16 + (lane&15)][kc*32 + (lane>>4)*8 + j]
// -> GEMM frag load = base + lane*16B (coalesced 1KB/wave, exact 16x16x32 operand layout).
__global__ __launch_bounds__(256)
void convert_kernel(const float* __restrict__ X, const float* __restrict__ W,
                    unsigned short* __restrict__ A2F, unsigned short* __restrict__ B2F,
                    unsigned long long* __restrict__ slots, float* __restrict__ out) {
    const int bid = blockIdx.x;
    const int tid = threadIdx.x;
    {   // zero-fill share of output (blocks 0..8191 cover all 2,097,152 float4s)
        int zidx = bid * 256 + tid;
        f32x4 z = {0.f, 0.f, 0.f, 0.f};
        if (zidx < OUT4) __builtin_nontemporal_store(z, (f32x4*)out + zidx);
    }
    const int lane = tid & 63;
    const float* src;
    unsigned short* dst;
    int unit;
    if (bid < 8192) {                      // X: units = 1024 mb x 32 kc
        unit = bid * 4 + (tid >> 6);
        src = X; dst = A2F;
    } else {                               // W: 1280 units -> 320 blocks
        if (bid == 8192 && tid < 17) slots[tid] = 0ull;   // 16 slots + counter
        unit = (bid - 8192) * 4 + (tid >> 6);
        src = W; dst = B2F;
    }
    int rt = unit >> 5, kc = unit & 31;
    int row = rt * 16 + (lane & 15);
    int col = kc * 32 + ((lane >> 4) << 3);
    const float* p = src + (size_t)row * CC + col;
    float4 v0 = *(const float4*)p;
    float4 v1 = *(const float4*)(p + 4);
    short8 hi;
    hi[0] = (short)bf16_rne(v0.x); hi[1] = (short)bf16_rne(v0.y);
    hi[2] = (short)bf16_rne(v0.z); hi[3] = (short)bf16_rne(v0.w);
    hi[4] = (short)bf16_rne(v1.x); hi[5] = (short)bf16_rne(v1.y);
    hi[6] = (short)bf16_rne(v1.z); hi[7] = (short)bf16_rne(v1.w);
    *(short8*)(dst + (size_t)unit * 512 + lane * 8) = hi;
}

// ------------------- symmetric 2-ahead bf16 MFMA GEMM + margin argmax + refine + scatter ----
// approx C = Xhi * Whi^T. No LDS, no barriers in the K-loop: A/B frags direct from L2/L3
// (fragment-major). Register pipeline: 3 buffers on BOTH streams, 3-slot rotation with a
// true 2-slot issue->consume distance: at slot t we refill buf[(t+2)%3] with data t+2
// BEFORE the MFMAs on buf[t%3], so the wait before each MFMA group is a counted
// vmcnt(16) (2 slot-rounds of cover ~ L3 latency), loads never drain. Body is only
// 3 slots (close to R0's 2) to keep sibling blocks in lockstep for A2F L2 sharing.
// Epilogue: block-max -> candidates within MARGIN -> cooperative EXACT fp32 dot from
// X,W -> packed atomicMax. Last block (device counter) scatters the 16 codebook rows.
__global__ __launch_bounds__(256, 3)
void gemm_argmax_mfma(const unsigned short* __restrict__ A2F,
                      const unsigned short* __restrict__ B2F,
                      const float* __restrict__ X,
                      const float* __restrict__ W,
                      const float* __restrict__ bias,
                      const float* __restrict__ codebook,
                      float* __restrict__ out,
                      unsigned long long* __restrict__ slots,
                      unsigned int* __restrict__ counter) {
    __shared__ float redf[4];
    __shared__ int cnt_s;
    __shared__ int cand_s[128];
    __shared__ unsigned int done_s;
    __shared__ unsigned long long s16[16];

    const int tid  = threadIdx.x;
    const int lane = tid & 63;
    const int wave = tid >> 6;

    // XCD swizzle: one XCD covers 16 m-tiles x all 5 n-tiles (n fastest) -> A2F L2 reuse.
    const int l   = blockIdx.x;        // 0..639
    const int xcd = l & 7;
    const int w   = l >> 3;
    const int mt  = xcd * 16 + w / 5;
    const int nt  = w % 5;
    const int m0 = mt * 128;
    const int n0 = nt * 128;

    const int wm = (wave >> 1) * 64;
    const int wn = (wave & 1) * 64;

    // 32-bit element offsets into A2F/B2F (uniform base + voffset addressing)
    unsigned aoff[4], boff[4];
#pragma unroll
    for (int t = 0; t < 4; t++) {
        aoff[t] = (unsigned)((((m0 + wm) >> 4) + t) * 32) * 512u + (unsigned)(lane * 8);
        boff[t] = (unsigned)((((n0 + wn) >> 4) + t) * 32) * 512u + (unsigned)(lane * 8);
    }

    f32x4 acc[4][4] = {};
    short8 a0[4], a1[4], a2[4], b0[4], b1[4], b2[4];

#define REFA(BUF)                                                        \
    {                                                                    \
        _Pragma("unroll")                                                \
        for (int f = 0; f < 4; f++) {                                    \
            BUF[f] = *(const short8*)(A2F + aoff[f]);                    \
            aoff[f] += 512;                                              \
        }                                                                \
    }
#define REFB(BUF)                                                        \
    {                                                                    \
        _Pragma("unroll")                                                \
        for (int f = 0; f < 4; f++) {                                    \
            BUF[f] = *(const short8*)(B2F + boff[f]);                    \
            boff[f] += 512;                                              \
        }                                                                \
    }
#define MFMAS(AB, BB)                                                    \
    {                                                                    \
        _Pragma("unroll")                                                \
        for (int ti = 0; ti < 4; ti++)                                   \
            _Pragma("unroll")                                            \
            for (int tj = 0; tj < 4; tj++)                               \
                acc[ti][tj] = __builtin_amdgcn_mfma_f32_16x16x32_bf16(   \
                    AB[ti], BB[tj], acc[ti][tj], 0, 0, 0);               \
    }

    // prologue: buffers 0,1 hold data 0,1 on both streams
    REFA(a0) REFB(b0) REFA(a1) REFB(b1)

    // Slot t (t = 3i..3i+2): refill buf[(t+2)%3] with data t+2 (issued FIRST),
    // then MFMA buf[t%3] (data t, loaded 2 slots ago -> vmcnt(16) counted wait).
    for (int i = 0; i < 10; i++) {         // t = 0..29
        REFA(a2) REFB(b2) MFMAS(a0, b0)    // t%3==0
        REFA(a0) REFB(b0) MFMAS(a1, b1)    // t%3==1
        REFA(a1) REFB(b1) MFMAS(a2, b2)    // t%3==2
    }
    MFMAS(a0, b0)                          // t = 30 (data 30, loaded t=28)
    MFMAS(a1, b1)                          // t = 31 (data 31, loaded t=29)
    // refill count = 2 + 30 = 32 -> data 0..31 exactly; no out-of-range reads.

#undef REFA
#undef REFB
#undef MFMAS

    // ---- epilogue: block max of approx logits ----
    // C/D layout (16x16x32): col = lane&15, row = (lane>>4)*4 + reg
    float bias4[4];
#pragma unroll
    for (int tj = 0; tj < 4; tj++) bias4[tj] = bias[n0 + wn + tj * 16 + (lane & 15)];

    float vmax = -3.0e38f;
#pragma unroll
    for (int ti = 0; ti < 4; ti++)
#pragma unroll
        for (int tj = 0; tj < 4; tj++)
#pragma unroll
            for (int r = 0; r < 4; r++)
                vmax = fmaxf(vmax, acc[ti][tj][r] + bias4[tj]);
#pragma unroll
    for (int off = 32; off > 0; off >>= 1)
        vmax = fmaxf(vmax, __shfl_down(vmax, off, 64));
    if (lane == 0) redf[wave] = vmax;
    if (tid == 0) cnt_s = 0;
    __syncthreads();
    float bm = fmaxf(fmaxf(redf[0], redf[1]), fmaxf(redf[2], redf[3]));
    float thresh = bm - MARGIN;

    // ---- collect candidates within MARGIN of block max ----
#pragma unroll
    for (int ti = 0; ti < 4; ti++) {
#pragma unroll
        for (int r = 0; r < 4; r++) {
            int m = m0 + wm + ti * 16 + (lane >> 4) * 4 + r;
#pragma unroll
            for (int tj = 0; tj < 4; tj++) {
                float v = acc[ti][tj][r] + bias4[tj];
                if (v >= thresh) {
                    int n = n0 + wn + tj * 16 + (lane & 15);
                    int idx = atomicAdd(&cnt_s, 1);
                    if (idx < 128) cand_s[idx] = (m << 10) | n;
                }
            }
        }
    }
    __syncthreads();
    int cnt = cnt_s < 128 ? cnt_s : 128;

    // ---- exact fp32 refine of each candidate (cooperative 1024-dot) ----
    for (int i = 0; i < cnt; i++) {
        int mc = cand_s[i] >> 10;
        int nc = cand_s[i] & 1023;
        float4 xv = *(const float4*)(X + (size_t)mc * CC + tid * 4);
        float4 wv = *(const float4*)(W + (size_t)nc * CC + tid * 4);
        float p = xv.x * wv.x + xv.y * wv.y + xv.z * wv.z + xv.w * wv.w;
#pragma unroll
        for (int off = 32; off > 0; off >>= 1) p += __shfl_down(p, off, 64);
        if (lane == 0) redf[wave] = p;
        __syncthreads();
        if (tid == 0) {
            float tot = redf[0] + redf[1] + redf[2] + redf[3] + bias[nc];
            unsigned int c = (unsigned int)((mc & 1023) * KN + nc);
            unsigned long long pk =
                ((unsigned long long)f32_orderable(tot) << 32) |
                (unsigned long long)(~c);
            atomicMax(slots + (mc >> 10), pk);
        }
        __syncthreads();
    }

    if (tid == 0) {
        __threadfence();
        done_s = atomicAdd(counter, 1u);
    }
    __syncthreads();

    // ---- last block scatters the 16 codebook rows ----
    if (done_s == NBLK - 1) {
        if (tid < 16) s16[tid] = atomicAdd(slots + tid, 0ull);   // coherent cross-XCD read
        __syncthreads();
        int rr  = tid >> 4;
        int seg = tid & 15;
        unsigned long long p = s16[rr];
        unsigned int c = ~(unsigned int)(p & 0xFFFFFFFFull);
        int tl = (int)(c / KN);
        int kg = (int)(c % KN);
        int b  = rr >> 1, h = rr & 1;
        int nstar = b * 2048 + h * 1024 + tl;
        int g = kg / EE;
        const float4* src = (const float4*)(codebook + (size_t)kg * DD) + seg * 4;
        float4* dst = (float4*)(out + (size_t)nstar * 512 + (size_t)g * DD) + seg * 4;
#pragma unroll
        for (int j = 0; j < 4; j++) dst[j] = src[j];
    }
}

// ------------------- fallback-only kernels (ws too small; not used in practice) ------------
__global__ __launch_bounds__(256)
void zs_kernel(const unsigned long long* __restrict__ slots,
               const float* __restrict__ codebook,
               float4* __restrict__ out4) {
    int i4 = blockIdx.x * 256 + threadIdx.x;
    int n  = i4 >> 7;
    int c4 = i4 & 127;
    int b  = n >> 11;
    int h  = (n >> 10) & 1;
    unsigned long long p = slots[b * 2 + h];
    unsigned int c = ~(unsigned int)(p & 0xFFFFFFFFull);
    int tl = (int)(c / KN);
    int kg = (int)(c % KN);
    int nstar = b * 2048 + h * 1024 + tl;
    int g = kg / EE;
    float4 v = make_float4(0.f, 0.f, 0.f, 0.f);
    if (n == nstar && (c4 >> 6) == g)
        v = ((const float4*)codebook)[kg * 64 + (c4 & 63)];
    out4[i4] = v;
}

#define BM 128
#define BN 64
#define BK 32
#define LDA (BM + 4)
#define LDB (BN + 4)

__global__ __launch_bounds__(128)
void gemm_argmax_f32(const float* __restrict__ X, const float* __restrict__ W,
                     const float* __restrict__ bias,
                     unsigned long long* __restrict__ slots) {
    __shared__ float Asf[BK][LDA];
    __shared__ float Bsf[BK][LDB];
    const int tid = threadIdx.x;
    const int m0 = blockIdx.y * BM;
    const int n0 = blockIdx.x * BN;
    const int tx = tid & 7, ty = tid >> 3;
    float acc[8][8];
#pragma unroll
    for (int i = 0; i < 8; i++)
#pragma unroll
        for (int j = 0; j < 8; j++) acc[i][j] = 0.0f;
    const int lm = tid >> 3, lk = (tid & 7) * 4;
    const float* Xb = X + (size_t)m0 * CC;
    const float* Wb = W + (size_t)n0 * CC;
    for (int k0 = 0; k0 < CC; k0 += BK) {
#pragma unroll
        for (int r = 0; r < 8; r++) {
            int m = r * 16 + lm;
            float4 v = *(const float4*)(Xb + (size_t)m * CC + k0 + lk);
            Asf[lk + 0][m] = v.x; Asf[lk + 1][m] = v.y; Asf[lk + 2][m] = v.z; Asf[lk + 3][m] = v.w;
        }
#pragma unroll
        for (int r = 0; r < 4; r++) {
            int m = r * 16 + lm;
            float4 v = *(const float4*)(Wb + (size_t)m * CC + k0 + lk);
            Bsf[lk + 0][m] = v.x; Bsf[lk + 1][m] = v.y; Bsf[lk + 2][m] = v.z; Bsf[lk + 3][m] = v.w;
        }
        __syncthreads();
#pragma unroll
        for (int kk = 0; kk < BK; kk++) {
            float4 A0 = *(const float4*)&Asf[kk][ty * 8];
            float4 A1 = *(const float4*)&Asf[kk][ty * 8 + 4];
            float4 B0 = *(const float4*)&Bsf[kk][tx * 8];
            float4 B1 = *(const float4*)&Bsf[kk][tx * 8 + 4];
            float a[8] = {A0.x, A0.y, A0.z, A0.w, A1.x, A1.y, A1.z, A1.w};
            float b[8] = {B0.x, B0.y, B0.z, B0.w, B1.x, B1.y, B1.z, B1.w};
#pragma unroll
            for (int i = 0; i < 8; i++)
#pragma unroll
                for (int j = 0; j < 8; j++) acc[i][j] = fmaf(a[i], b[j], acc[i][j]);
        }
        __syncthreads();
    }
    unsigned long long best = 0ull;
#pragma unroll
    for (int i = 0; i < 8; i++) {
        int mg = m0 + ty * 8 + i;
        int tl = mg & 1023;
#pragma unroll
        for (int j = 0; j < 8; j++) {
            int kg = n0 + tx * 8 + j;
            float v = acc[i][j] + bias[kg];
            unsigned int c = (unsigned int)(tl * KN + kg);
            unsigned long long p = ((unsigned long long)f32_orderable(v) << 32) |
                                   (unsigned long long)(~c);
            if (p > best) best = p;
        }
    }
#pragma unroll
    for (int off = 32; off > 0; off >>= 1) {
        unsigned long long o = __shfl_down(best, off, 64);
        if (o > best) best = o;
    }
    __shared__ unsigned long long red2[2];
    if ((tid & 63) == 0) red2[tid >> 6] = best;
    __syncthreads();
    if (tid == 0) {
        unsigned long long b0 = red2[0], b1 = red2[1];
        atomicMax(slots + (m0 >> 10), b0 > b1 ? b0 : b1);
    }
}

extern "C" void kernel_launch(void* const* d_in, const int* in_sizes, int n_in,
                              void* d_out, int out_size, void* d_ws, size_t ws_size,
                              hipStream_t stream) {
    const float* X        = (const float*)d_in[0];  // (8,2048,1024)
    const float* W        = (const float*)d_in[1];  // (640,1024)
    const float* bias     = (const float*)d_in[2];  // (640,)
    const float* codebook = (const float*)d_in[3];  // (640,256)
    float* out = (float*)d_out;                     // (8,2048,512) fp32

    unsigned long long* slots = (unsigned long long*)d_ws;   // [0..15] slots, [16] counter
    unsigned int* counter = (unsigned int*)(slots + 16);
    const size_t A_off   = 256;
    const size_t A_bytes = (size_t)MTOT * CC * 2;       // 33,554,432 (hi-only frag-major)
    const size_t B_off   = A_off + A_bytes;
    const size_t B_bytes = (size_t)KN * CC * 2;         // 1,310,720
    const size_t need = B_off + B_bytes;

    if (ws_size >= need) {
        unsigned short* A2F = (unsigned short*)((char*)d_ws + A_off);
        unsigned short* B2F = (unsigned short*)((char*)d_ws + B_off);
        hipLaunchKernelGGL(convert_kernel, dim3(8192 + 320), dim3(256), 0, stream,
                           X, W, A2F, B2F, slots, out);
        hipLaunchKernelGGL(gemm_argmax_mfma, dim3(NBLK), dim3(256), 0, stream,
                           A2F, B2F, X, W, bias, codebook, out, slots, counter);
    } else {
        hipLaunchKernelGGL(init_slots_kernel, dim3(1), dim3(64), 0, stream, slots);
        hipLaunchKernelGGL(gemm_argmax_f32, dim3(KN / BN, MTOT / BM), dim3(128), 0, stream,
                           X, W, bias, slots);
        hipLaunchKernelGGL(zs_kernel, dim3(OUT4 / 256), dim3(256), 0, stream,
                           slots, codebook, (float4*)out);
    }
}

// Round 5
// 167.985 us; speedup vs baseline: 1.5472x; 1.0153x over previous
//
#include <hip/hip_runtime.h>
#include <stdint.h>

// Problem constants
#define CC    1024
#define EE    320
#define KN    640         // G*E
#define DD    256
#define MTOT  16384       // B*T
#define NBLK  640         // GEMM grid
#define OUT4  2097152     // output float4 count
#define MARGIN 2.0f       // candidate gate: 15 sigma of hi*hi dropped-term error

typedef __attribute__((ext_vector_type(8))) short short8;
typedef __attribute__((ext_vector_type(4))) float f32x4;

__device__ __forceinline__ unsigned int f32_orderable(float x) {
    unsigned int b = __float_as_uint(x);
    return (b & 0x80000000u) ? ~b : (b | 0x80000000u);
}

__device__ __forceinline__ unsigned short bf16_rne(float x) {
    unsigned int u = __float_as_uint(x);
    return (unsigned short)((u + 0x7FFFu + ((u >> 16) & 1u)) >> 16);
}

__global__ void init_slots_kernel(unsigned long long* __restrict__ slots) {
    if (threadIdx.x < 17) slots[threadIdx.x] = 0ull;
}

// ------------------- fused convert (hi-only) + zero-fill + slot init -------------------
// Fragment-major hi-only layout (A2F from X, B2F from W):
//   unit = rowTile*32 + kc   (rowTile = row/16, kc = k/32)
//   buf[unit*512 + lane*8 + j] = bf16_hi of M[rowTile*16 + (lane&15)][kc*32 + (lane>>4)*8 + j]
// -> GEMM frag load = base + lane*16B (coalesced 1KB/wave, exact 16x16x32 operand layout).
__global__ __launch_bounds__(256)
void convert_kernel(const float* __restrict__ X, const float* __restrict__ W,
                    unsigned short* __restrict__ A2F, unsigned short* __restrict__ B2F,
                    unsigned long long* __restrict__ slots, float* __restrict__ out) {
    const int bid = blockIdx.x;
    const int tid = threadIdx.x;
    {   // zero-fill share of output (blocks 0..8191 cover all 2,097,152 float4s)
        int zidx = bid * 256 + tid;
        f32x4 z = {0.f, 0.f, 0.f, 0.f};
        if (zidx < OUT4) __builtin_nontemporal_store(z, (f32x4*)out + zidx);
    }
    const int lane = tid & 63;
    const float* src;
    unsigned short* dst;
    int unit;
    if (bid < 8192) {                      // X: units = 1024 mb x 32 kc
        unit = bid * 4 + (tid >> 6);
        src = X; dst = A2F;
    } else {                               // W: 1280 units -> 320 blocks
        if (bid == 8192 && tid < 17) slots[tid] = 0ull;   // 16 slots + counter
        unit = (bid - 8192) * 4 + (tid >> 6);
        src = W; dst = B2F;
    }
    int rt = unit >> 5, kc = unit & 31;
    int row = rt * 16 + (lane & 15);
    int col = kc * 32 + ((lane >> 4) << 3);
    const float* p = src + (size_t)row * CC + col;
    float4 v0 = *(const float4*)p;
    float4 v1 = *(const float4*)(p + 4);
    short8 hi;
    hi[0] = (short)bf16_rne(v0.x); hi[1] = (short)bf16_rne(v0.y);
    hi[2] = (short)bf16_rne(v0.z); hi[3] = (short)bf16_rne(v0.w);
    hi[4] = (short)bf16_rne(v1.x); hi[5] = (short)bf16_rne(v1.y);
    hi[6] = (short)bf16_rne(v1.z); hi[7] = (short)bf16_rne(v1.w);
    *(short8*)(dst + (size_t)unit * 512 + lane * 8) = hi;
}

// ------------------- 8-wave bf16 MFMA GEMM + margin argmax + exact refine + scatter ----------
// approx C = Xhi * Whi^T. Same 128x128 tile / 640-block grid / ping-pong STEP as the proven
// 50us version, but 512 threads = 8 waves (wave-tile 64x32, 2m x 4n) -> 5 waves/SIMD
// instead of 2.5. The kernel is latency-bound (R0: MfmaUtil 15%, VALU 8%, HBM 6%); the
// compiler collapses any deeper source-level pipeline (R3/R4 evidence), so the only lever
// it cannot undo is MORE WAVES interleaving the same 1-ahead schedule. L2 traffic is
// unchanged (L1 dedups intra-block fragment sharing). Epilogue: block-max -> candidates
// within MARGIN -> cooperative EXACT fp32 dot from X,W -> packed atomicMax. Last block
// (device counter) scatters the 16 codebook rows.
__global__ __launch_bounds__(512, 6)
void gemm_argmax_mfma(const unsigned short* __restrict__ A2F,
                      const unsigned short* __restrict__ B2F,
                      const float* __restrict__ X,
                      const float* __restrict__ W,
                      const float* __restrict__ bias,
                      const float* __restrict__ codebook,
                      float* __restrict__ out,
                      unsigned long long* __restrict__ slots,
                      unsigned int* __restrict__ counter) {
    __shared__ float redf[8];
    __shared__ int cnt_s;
    __shared__ int cand_s[128];
    __shared__ unsigned int done_s;
    __shared__ unsigned long long s16[16];

    const int tid  = threadIdx.x;
    const int lane = tid & 63;
    const int wave = tid >> 6;        // 0..7

    // XCD swizzle: one XCD covers 16 m-tiles x all 5 n-tiles (n fastest) -> A2F L2 reuse.
    const int l   = blockIdx.x;        // 0..639
    const int xcd = l & 7;
    const int w   = l >> 3;
    const int mt  = xcd * 16 + w / 5;
    const int nt  = w % 5;
    const int m0 = mt * 128;
    const int n0 = nt * 128;

    const int wm = (wave >> 2) * 64;   // 0,64
    const int wn = (wave & 3) * 32;    // 0,32,64,96

    // 32-bit element offsets into A2F/B2F (uniform base + voffset addressing)
    unsigned aoff[4], boff[2];
#pragma unroll
    for (int t = 0; t < 4; t++)
        aoff[t] = (unsigned)((((m0 + wm) >> 4) + t) * 32) * 512u + (unsigned)(lane * 8);
#pragma unroll
    for (int t = 0; t < 2; t++)
        boff[t] = (unsigned)((((n0 + wn) >> 4) + t) * 32) * 512u + (unsigned)(lane * 8);

    f32x4 acc[4][2] = {};
    short8 a0[4], b0[2], a1[4], b1[2];

    // prologue: load it=0 frags
#pragma unroll
    for (int t = 0; t < 4; t++) { a0[t] = *(const short8*)(A2F + aoff[t]); aoff[t] += 512; }
#pragma unroll
    for (int t = 0; t < 2; t++) { b0[t] = *(const short8*)(B2F + boff[t]); boff[t] += 512; }

#define STEP(CURA, CURB, NXTA, NXTB, IT)                                         \
    {                                                                            \
        if ((IT) < 31) {                                                         \
            _Pragma("unroll")                                                    \
            for (int t = 0; t < 4; t++) {                                        \
                NXTA[t] = *(const short8*)(A2F + aoff[t]);                       \
                aoff[t] += 512;                                                  \
            }                                                                    \
            _Pragma("unroll")                                                    \
            for (int t = 0; t < 2; t++) {                                        \
                NXTB[t] = *(const short8*)(B2F + boff[t]);                       \
                boff[t] += 512;                                                  \
            }                                                                    \
        }                                                                        \
        _Pragma("unroll")                                                        \
        for (int ti = 0; ti < 4; ti++)                                           \
            _Pragma("unroll")                                                    \
            for (int tj = 0; tj < 2; tj++)                                       \
                acc[ti][tj] = __builtin_amdgcn_mfma_f32_16x16x32_bf16(           \
                    CURA[ti], CURB[tj], acc[ti][tj], 0, 0, 0);                   \
    }

    for (int it2 = 0; it2 < 16; it2++) {
        STEP(a0, b0, a1, b1, it2 * 2)
        STEP(a1, b1, a0, b0, it2 * 2 + 1)
    }
#undef STEP

    // ---- epilogue: block max of approx logits ----
    // C/D layout (16x16x32): col = lane&15, row = (lane>>4)*4 + reg
    float bias2[2];
#pragma unroll
    for (int tj = 0; tj < 2; tj++) bias2[tj] = bias[n0 + wn + tj * 16 + (lane & 15)];

    float vmax = -3.0e38f;
#pragma unroll
    for (int ti = 0; ti < 4; ti++)
#pragma unroll
        for (int tj = 0; tj < 2; tj++)
#pragma unroll
            for (int r = 0; r < 4; r++)
                vmax = fmaxf(vmax, acc[ti][tj][r] + bias2[tj]);
#pragma unroll
    for (int off = 32; off > 0; off >>= 1)
        vmax = fmaxf(vmax, __shfl_down(vmax, off, 64));
    if (lane == 0) redf[wave] = vmax;
    if (tid == 0) cnt_s = 0;
    __syncthreads();
    float bm = redf[0];
#pragma unroll
    for (int i = 1; i < 8; i++) bm = fmaxf(bm, redf[i]);
    float thresh = bm - MARGIN;

    // ---- collect candidates within MARGIN of block max ----
#pragma unroll
    for (int ti = 0; ti < 4; ti++) {
#pragma unroll
        for (int r = 0; r < 4; r++) {
            int m = m0 + wm + ti * 16 + (lane >> 4) * 4 + r;
#pragma unroll
            for (int tj = 0; tj < 2; tj++) {
                float v = acc[ti][tj][r] + bias2[tj];
                if (v >= thresh) {
                    int n = n0 + wn + tj * 16 + (lane & 15);
                    int idx = atomicAdd(&cnt_s, 1);
                    if (idx < 128) cand_s[idx] = (m << 10) | n;
                }
            }
        }
    }
    __syncthreads();
    int cnt = cnt_s < 128 ? cnt_s : 128;

    // ---- exact fp32 refine of each candidate (cooperative 1024-dot, 512 threads x 2) ----
    for (int i = 0; i < cnt; i++) {
        int mc = cand_s[i] >> 10;
        int nc = cand_s[i] & 1023;
        float2 xv = *(const float2*)(X + (size_t)mc * CC + tid * 2);
        float2 wv = *(const float2*)(W + (size_t)nc * CC + tid * 2);
        float p = xv.x * wv.x + xv.y * wv.y;
#pragma unroll
        for (int off = 32; off > 0; off >>= 1) p += __shfl_down(p, off, 64);
        if (lane == 0) redf[wave] = p;
        __syncthreads();
        if (tid == 0) {
            float tot = redf[0] + redf[1] + redf[2] + redf[3] +
                        redf[4] + redf[5] + redf[6] + redf[7] + bias[nc];
            unsigned int c = (unsigned int)((mc & 1023) * KN + nc);
            unsigned long long pk =
                ((unsigned long long)f32_orderable(tot) << 32) |
                (unsigned long long)(~c);
            atomicMax(slots + (mc >> 10), pk);
        }
        __syncthreads();
    }

    if (tid == 0) {
        __threadfence();
        done_s = atomicAdd(counter, 1u);
    }
    __syncthreads();

    // ---- last block scatters the 16 codebook rows ----
    if (done_s == NBLK - 1) {
        if (tid < 16) s16[tid] = atomicAdd(slots + tid, 0ull);   // coherent cross-XCD read
        __syncthreads();
        if (tid < 256) {
            int rr  = tid >> 4;
            int seg = tid & 15;
            unsigned long long p = s16[rr];
            unsigned int c = ~(unsigned int)(p & 0xFFFFFFFFull);
            int tl = (int)(c / KN);
            int kg = (int)(c % KN);
            int b  = rr >> 1, h = rr & 1;
            int nstar = b * 2048 + h * 1024 + tl;
            int g = kg / EE;
            const float4* src = (const float4*)(codebook + (size_t)kg * DD) + seg * 4;
            float4* dst = (float4*)(out + (size_t)nstar * 512 + (size_t)g * DD) + seg * 4;
#pragma unroll
            for (int j = 0; j < 4; j++) dst[j] = src[j];
        }
    }
}

// ------------------- fallback-only kernels (ws too small; not used in practice) ------------
__global__ __launch_bounds__(256)
void zs_kernel(const unsigned long long* __restrict__ slots,
               const float* __restrict__ codebook,
               float4* __restrict__ out4) {
    int i4 = blockIdx.x * 256 + threadIdx.x;
    int n  = i4 >> 7;
    int c4 = i4 & 127;
    int b  = n >> 11;
    int h  = (n >> 10) & 1;
    unsigned long long p = slots[b * 2 + h];
    unsigned int c = ~(unsigned int)(p & 0xFFFFFFFFull);
    int tl = (int)(c / KN);
    int kg = (int)(c % KN);
    int nstar = b * 2048 + h * 1024 + tl;
    int g = kg / EE;
    float4 v = make_float4(0.f, 0.f, 0.f, 0.f);
    if (n == nstar && (c4 >> 6) == g)
        v = ((const float4*)codebook)[kg * 64 + (c4 & 63)];
    out4[i4] = v;
}

#define BM 128
#define BN 64
#define BK 32
#define LDA (BM + 4)
#define LDB (BN + 4)

__global__ __launch_bounds__(128)
void gemm_argmax_f32(const float* __restrict__ X, const float* __restrict__ W,
                     const float* __restrict__ bias,
                     unsigned long long* __restrict__ slots) {
    __shared__ float Asf[BK][LDA];
    __shared__ float Bsf[BK][LDB];
    const int tid = threadIdx.x;
    const int m0 = blockIdx.y * BM;
    const int n0 = blockIdx.x * BN;
    const int tx = tid & 7, ty = tid >> 3;
    float acc[8][8];
#pragma unroll
    for (int i = 0; i < 8; i++)
#pragma unroll
        for (int j = 0; j < 8; j++) acc[i][j] = 0.0f;
    const int lm = tid >> 3, lk = (tid & 7) * 4;
    const float* Xb = X + (size_t)m0 * CC;
    const float* Wb = W + (size_t)n0 * CC;
    for (int k0 = 0; k0 < CC; k0 += BK) {
#pragma unroll
        for (int r = 0; r < 8; r++) {
            int m = r * 16 + lm;
            float4 v = *(const float4*)(Xb + (size_t)m * CC + k0 + lk);
            Asf[lk + 0][m] = v.x; Asf[lk + 1][m] = v.y; Asf[lk + 2][m] = v.z; Asf[lk + 3][m] = v.w;
        }
#pragma unroll
        for (int r = 0; r < 4; r++) {
            int m = r * 16 + lm;
            float4 v = *(const float4*)(Wb + (size_t)m * CC + k0 + lk);
            Bsf[lk + 0][m] = v.x; Bsf[lk + 1][m] = v.y; Bsf[lk + 2][m] = v.z; Bsf[lk + 3][m] = v.w;
        }
        __syncthreads();
#pragma unroll
        for (int kk = 0; kk < BK; kk++) {
            float4 A0 = *(const float4*)&Asf[kk][ty * 8];
            float4 A1 = *(const float4*)&Asf[kk][ty * 8 + 4];
            float4 B0 = *(const float4*)&Bsf[kk][tx * 8];
            float4 B1 = *(const float4*)&Bsf[kk][tx * 8 + 4];
            float a[8] = {A0.x, A0.y, A0.z, A0.w, A1.x, A1.y, A1.z, A1.w};
            float b[8] = {B0.x, B0.y, B0.z, B0.w, B1.x, B1.y, B1.z, B1.w};
#pragma unroll
            for (int i = 0; i < 8; i++)
#pragma unroll
                for (int j = 0; j < 8; j++) acc[i][j] = fmaf(a[i], b[j], acc[i][j]);
        }
        __syncthreads();
    }
    unsigned long long best = 0ull;
#pragma unroll
    for (int i = 0; i < 8; i++) {
        int mg = m0 + ty * 8 + i;
        int tl = mg & 1023;
#pragma unroll
        for (int j = 0; j < 8; j++) {
            int kg = n0 + tx * 8 + j;
            float v = acc[i][j] + bias[kg];
            unsigned int c = (unsigned int)(tl * KN + kg);
            unsigned long long p = ((unsigned long long)f32_orderable(v) << 32) |
                                   (unsigned long long)(~c);
            if (p > best) best = p;
        }
    }
#pragma unroll
    for (int off = 32; off > 0; off >>= 1) {
        unsigned long long o = __shfl_down(best, off, 64);
        if (o > best) best = o;
    }
    __shared__ unsigned long long red2[2];
    if ((tid & 63) == 0) red2[tid >> 6] = best;
    __syncthreads();
    if (tid == 0) {
        unsigned long long b0 = red2[0], b1 = red2[1];
        atomicMax(slots + (m0 >> 10), b0 > b1 ? b0 : b1);
    }
}

extern "C" void kernel_launch(void* const* d_in, const int* in_sizes, int n_in,
                              void* d_out, int out_size, void* d_ws, size_t ws_size,
                              hipStream_t stream) {
    const float* X        = (const float*)d_in[0];  // (8,2048,1024)
    const float* W        = (const float*)d_in[1];  // (640,1024)
    const float* bias     = (const float*)d_in[2];  // (640,)
    const float* codebook = (const float*)d_in[3];  // (640,256)
    float* out = (float*)d_out;                     // (8,2048,512) fp32

    unsigned long long* slots = (unsigned long long*)d_ws;   // [0..15] slots, [16] counter
    unsigned int* counter = (unsigned int*)(slots + 16);
    const size_t A_off   = 256;
    const size_t A_bytes = (size_t)MTOT * CC * 2;       // 33,554,432 (hi-only frag-major)
    const size_t B_off   = A_off + A_bytes;
    const size_t B_bytes = (size_t)KN * CC * 2;         // 1,310,720
    const size_t need = B_off + B_bytes;

    if (ws_size >= need) {
        unsigned short* A2F = (unsigned short*)((char*)d_ws + A_off);
        unsigned short* B2F = (unsigned short*)((char*)d_ws + B_off);
        hipLaunchKernelGGL(convert_kernel, dim3(8192 + 320), dim3(256), 0, stream,
                           X, W, A2F, B2F, slots, out);
        hipLaunchKernelGGL(gemm_argmax_mfma, dim3(NBLK), dim3(512), 0, stream,
                           A2F, B2F, X, W, bias, codebook, out, slots, counter);
    } else {
        hipLaunchKernelGGL(init_slots_kernel, dim3(1), dim3(64), 0, stream, slots);
        hipLaunchKernelGGL(gemm_argmax_f32, dim3(KN / BN, MTOT / BM), dim3(128), 0, stream,
                           X, W, bias, slots);
        hipLaunchKernelGGL(zs_kernel, dim3(OUT4 / 256), dim3(256), 0, stream,
                           slots, codebook, (float4*)out);
    }
}